// Round 8
// baseline (129.889 us; speedup 1.0000x reference)
//
#include <hip/hip_runtime.h>
#include <hip/hip_bf16.h>
#include <math.h>

// FFM: B=32768, n=512, f=30, k=40
// inter[b] = X[b]^T W X[b],  W = 0.5*(C - diag(C)), C symmetric
// out = sigmoid(X@w1 + b + inter)
//
// R13: per-block work doubled. Five schedule variants at BM=64 all pinned at
// 45-52us; the invariant was W traffic (each block streams all 512KB of W ->
// 256MB L2 total) and 2 sequential block-rounds. BM=128, grid=256 (1
// block/CU, single round) halves W traffic; row-half wave pairs share
// col-spans (L1 reuse); 16 MFMA/step/wave doubles latency cover. fa dist-1,
// fb dist-2 register prefetch (parity slots, compiler-counted waits, no
// barriers in loop). Per-block K-rotation decorrelates L2 line contention.

#define N_FEAT 512
#define FK 1200
#define KDIM 40
#define B_ROWS 32768
#define BM 128
#define NSTEP 16

typedef __attribute__((ext_vector_type(8))) short short8;
typedef __attribute__((ext_vector_type(16))) float f32x16;

__device__ __forceinline__ unsigned short bf16_rne(float f) {
    union { float f; unsigned int u; } c; c.f = f;
    unsigned int u = c.u;
    u += 0x7fffu + ((u >> 16) & 1u);
    return (unsigned short)(u >> 16);
}

__device__ __forceinline__ float bf16_to_f(unsigned short h) {
    union { unsigned int u; float f; } c;
    c.u = ((unsigned int)h) << 16;
    return c.f;
}

// ---------------- Kernel 1: build Wpk (512x512 bf16, chunked layout) ----------------
// Thread (i = blockIdx.y, j = blockIdx.x*256+tid) computes C[i][j], stores
// B[j][i] (symmetry) at chunk unit (j>>3)*512 + i, elem j&7. Lanes 0-7
// (consecutive j) write one contiguous 16B unit -> merged stores.
__global__ __launch_bounds__(256) void build_wpk(const float* __restrict__ v,
                                                 const int* __restrict__ f2f,
                                                 unsigned short* __restrict__ Wpk) {
    __shared__ float a_lds[FK];          // 4.8 KB
    __shared__ float c_lds[256 * 44];    // 45 KB (pad 40->44)

    const int i   = blockIdx.y;
    const int j0  = blockIdx.x * 256;
    const int tid = threadIdx.x;
    const int fi  = f2f[i];

    for (int q = tid; q < FK; q += 256) a_lds[q] = v[(size_t)i * FK + q];
    for (int q = tid; q < 2560; q += 256) {
        const int jl = q / 10, c4 = q % 10;
        *(float4*)&c_lds[jl * 44 + c4 * 4] =
            *(const float4*)&v[(size_t)(j0 + jl) * FK + fi * KDIM + c4 * 4];
    }
    __syncthreads();

    const int j  = j0 + tid;
    const int fj = f2f[j];
    const float4* a = (const float4*)&a_lds[fj * KDIM];
    const float4* c = (const float4*)&c_lds[tid * 44];
    float acc = 0.f;
#pragma unroll
    for (int q = 0; q < KDIM / 4; ++q) {
        float4 av = a[q], cv = c[q];
        acc = fmaf(av.x, cv.x, acc);
        acc = fmaf(av.y, cv.y, acc);
        acc = fmaf(av.z, cv.z, acc);
        acc = fmaf(av.w, cv.w, acc);
    }
    const unsigned short val = (i == j) ? (unsigned short)0 : bf16_rne(0.5f * acc);
    Wpk[((size_t)(j >> 3) * 512 + i) * 8 + (j & 7)] = val;
}

// ---------------- Kernel 2: fused GEMM + quadratic-form epilogue ----------------
// grid: 256 blocks x 512 threads (8 waves), 1 block/CU, single round.
// Wave (wm=w&1, wn=w>>1): rows [wm*64,+64), cols [wn*128,+128) = 2mi x 4ci
// frags of 32x32x16 (acc 128 AGPR). As: kc-major units, unit(kc,r) =
// kc*128 + (r^(kc&7)). B direct global->VGPR from Wpk (unit (ks*512+col)).
__global__ __launch_bounds__(512, 1) void ffm_fused(const float* __restrict__ X,
                                                    const unsigned short* __restrict__ Wpk,
                                                    const float* __restrict__ w1,
                                                    const float* __restrict__ bvec,
                                                    float* __restrict__ out) {
    __shared__ __align__(16) unsigned short As[BM * N_FEAT];      // 128 KB
    __shared__ float part[4 * BM];                                // 2 KB

    const int tid  = threadIdx.x;
    const int lane = tid & 63;
    const int wave = tid >> 6;      // 0..7
    const int half = lane >> 5;     // 0/1
    const int l31  = lane & 31;
    const int wm   = wave & 1;      // row half
    const int wn   = wave >> 1;     // col quarter 0..3

    const size_t row0 = (size_t)blockIdx.x * BM;
    const int rot = blockIdx.x & (NSTEP - 1);    // K-phase rotation

    // Per-lane B base: unit = (.. + half)*512 + wn*128 + ci*32 + l31.
    const unsigned short* wp = Wpk + ((size_t)half * 512 + wn * 128 + l31) * 8;

    // ---- Prologue: build As (X block, bf16, kc-major + XOR swizzle) ----
    {
        const float4* X4 = (const float4*)(X + row0 * N_FEAT);
#pragma unroll
        for (int u = 0; u < 16; ++u) {
            const int g  = u * 512 + tid;
            const int r  = g >> 6;      // wave-uniform row 0..127
            const int kc = g & 63;      // = lane: 16B chunk in row
            float4 f0 = X4[r * 128 + kc * 2];
            float4 f1 = X4[r * 128 + kc * 2 + 1];
            union { unsigned short us[8]; short8 v; } pk;
            pk.us[0] = bf16_rne(f0.x);
            pk.us[1] = bf16_rne(f0.y);
            pk.us[2] = bf16_rne(f0.z);
            pk.us[3] = bf16_rne(f0.w);
            pk.us[4] = bf16_rne(f1.x);
            pk.us[5] = bf16_rne(f1.y);
            pk.us[6] = bf16_rne(f1.z);
            pk.us[7] = bf16_rne(f1.w);
            *(short8*)(As + ((size_t)kc * BM + (r ^ (kc & 7))) * 8) = pk.v;
        }
    }
    asm volatile("s_waitcnt lgkmcnt(0)" ::: "memory");
    __builtin_amdgcn_s_barrier();          // As visible to all waves

    f32x16 acc[2][4];
#pragma unroll
    for (int mi = 0; mi < 2; ++mi)
#pragma unroll
        for (int ci = 0; ci < 4; ++ci)
#pragma unroll
            for (int r = 0; r < 16; ++r) acc[mi][ci][r] = 0.f;

    short8 fb[2][2][4];   // [parity slot][si][ci], prefetch distance 2
    short8 fa[2][2][2];   // [parity slot][si][mi], prefetch distance 1

    // ---- Prime the pipeline: fb(0)->slot0, fb(1)->slot1, fa(0)->slot0 ----
    {
        const int tr0 = rot;
        const int tr1 = (rot + 1) & (NSTEP - 1);
#pragma unroll
        for (int si = 0; si < 2; ++si)
#pragma unroll
            for (int ci = 0; ci < 4; ++ci) {
                fb[0][si][ci] = *(const short8*)(wp +
                    ((size_t)(tr0 * 4 + si * 2) * 512 + ci * 32) * 8);
                fb[1][si][ci] = *(const short8*)(wp +
                    ((size_t)(tr1 * 4 + si * 2) * 512 + ci * 32) * 8);
            }
#pragma unroll
        for (int si = 0; si < 2; ++si) {
            const int kcg = tr0 * 4 + si * 2 + half;
            const int ksw = kcg & 7;
#pragma unroll
            for (int mi = 0; mi < 2; ++mi)
                fa[0][si][mi] = *(const short8*)(As +
                    ((size_t)kcg * BM + ((wm * 64 + mi * 32 + l31) ^ ksw)) * 8);
        }
    }

#pragma unroll
    for (int t = 0; t < NSTEP; ++t) {
        const int cur = t & 1;
        const int nxt = cur ^ 1;

        // Prefetch fa(t+1) (distance 1; ds latency hides under MFMA(t)).
        if (t + 1 < NSTEP) {
            const int trn = (t + 1 + rot) & (NSTEP - 1);
#pragma unroll
            for (int si = 0; si < 2; ++si) {
                const int kcg = trn * 4 + si * 2 + half;
                const int ksw = kcg & 7;
#pragma unroll
                for (int mi = 0; mi < 2; ++mi)
                    fa[nxt][si][mi] = *(const short8*)(As +
                        ((size_t)kcg * BM + ((wm * 64 + mi * 32 + l31) ^ ksw)) * 8);
            }
        }

        __builtin_amdgcn_s_setprio(1);
#pragma unroll
        for (int si = 0; si < 2; ++si)
#pragma unroll
            for (int mi = 0; mi < 2; ++mi)
#pragma unroll
                for (int ci = 0; ci < 4; ++ci)
                    acc[mi][ci] = __builtin_amdgcn_mfma_f32_32x32x16_bf16(
                        fa[cur][si][mi], fb[cur][si][ci], acc[mi][ci], 0, 0, 0);
        __builtin_amdgcn_s_setprio(0);

        // Reload this parity slot with fb(t+2) (distance 2: ~2 steps of cover).
        if (t + 2 < NSTEP) {
            const int trn2 = (t + 2 + rot) & (NSTEP - 1);
#pragma unroll
            for (int si = 0; si < 2; ++si)
#pragma unroll
                for (int ci = 0; ci < 4; ++ci)
                    fb[cur][si][ci] = *(const short8*)(wp +
                        ((size_t)(trn2 * 4 + si * 2) * 512 + ci * 32) * 8);
        }
    }

    // ---- Epilogue: rs[row] = sum_col x[row][col]*(y + w1), x-hat from As (bf16).
    // C/D 32x32 layout: col = l31 (+ci*32+wn*128), row = (reg&3)+8*(reg>>2)+4*half
    // (+wm*64+mi*32).
    float w1v[4];
#pragma unroll
    for (int ci = 0; ci < 4; ++ci) w1v[ci] = w1[wn * 128 + ci * 32 + l31];
    const float bias = bvec[0];

    float rs[2][16];
#pragma unroll
    for (int mi = 0; mi < 2; ++mi) {
#pragma unroll
        for (int reg = 0; reg < 16; ++reg) {
            const int row = wm * 64 + mi * 32 + (reg & 3) + 8 * (reg >> 2) + 4 * half;
            float s = 0.f;
#pragma unroll
            for (int ci = 0; ci < 4; ++ci) {
                const int gc = wn * 128 + ci * 32 + l31;      // k-index 0..511
                const int kc = gc >> 3;
                const float xf = bf16_to_f(As[((size_t)kc * BM + (row ^ (kc & 7))) * 8 + (gc & 7)]);
                s = fmaf(xf, acc[mi][ci][reg] + w1v[ci], s);
            }
            rs[mi][reg] = s;
        }
    }

    // Reduce over the 32 cols held across l31 (each 32-lane group = one row set).
#pragma unroll
    for (int mi = 0; mi < 2; ++mi)
#pragma unroll
        for (int reg = 0; reg < 16; ++reg) {
            float r = rs[mi][reg];
#pragma unroll
            for (int off = 1; off < 32; off <<= 1)
                r += __shfl_xor(r, off, 32);
            rs[mi][reg] = r;
        }
    if (l31 == 0) {
#pragma unroll
        for (int mi = 0; mi < 2; ++mi)
#pragma unroll
            for (int reg = 0; reg < 16; ++reg) {
                const int row = wm * 64 + mi * 32 + (reg & 3) + 8 * (reg >> 2) + 4 * half;
                part[wn * BM + row] = rs[mi][reg];
            }
    }
    __syncthreads();

    if (tid < BM) {
        float tsum = bias;
#pragma unroll
        for (int q = 0; q < 4; ++q) tsum += part[q * BM + tid];
        out[row0 + tid] = 1.0f / (1.0f + expf(-tsum));
    }
}

extern "C" void kernel_launch(void* const* d_in, const int* in_sizes, int n_in,
                              void* d_out, int out_size, void* d_ws, size_t ws_size,
                              hipStream_t stream) {
    const float* X   = (const float*)d_in[0];   // 32768 x 512
    const float* w1  = (const float*)d_in[1];   // 512
    const float* b   = (const float*)d_in[2];   // 1
    const float* v   = (const float*)d_in[3];   // 512 x 30 x 40
    const int*   f2f = (const int*)d_in[4];     // 512
    float* out = (float*)d_out;                 // 32768

    unsigned short* Wpk = (unsigned short*)d_ws;   // 512 KB scratch (chunked layout)

    build_wpk<<<dim3(2, N_FEAT), 256, 0, stream>>>(v, f2f, Wpk);
    ffm_fused<<<B_ROWS / BM, 512, 0, stream>>>(X, Wpk, w1, b, out);
}

// Round 9
// 127.512 us; speedup vs baseline: 1.0186x; 1.0186x over previous
//
#include <hip/hip_runtime.h>
#include <hip/hip_bf16.h>
#include <math.h>

// FFM: B=32768, n=512, f=30, k=40
// inter[b] = X[b]^T W X[b],  W = 0.5*(C - diag(C)), C symmetric
// out = sigmoid(X@w1 + b + inter)
//
// R14: code-size fix. Six structurally different schedules (R5..R13) all
// pinned at 43-52us with MFMA/VALU/HBM all <15% and ~35us unaccounted by
// any pipe counter -> instruction-fetch bound: every variant fully unrolled
// loop+prologue+epilogue to ~20-24KB straight-line code vs 32KB I$.
// This round: K-loop ROLLED (7 iters x 2-step body, parity slots static,
// roaming pointers, unroll 1), prologue unroll 2, setprio dropped (m190:
// harmful on non-phase-split GEMM), rot dropped. Data plan = R13: BM=128,
// grid 256 (1 block/CU), fb direct global->VGPR dist-2, fa LDS dist-1.

#define N_FEAT 512
#define FK 1200
#define KDIM 40
#define B_ROWS 32768
#define BM 128
#define NSTEP 16

typedef __attribute__((ext_vector_type(8))) short short8;
typedef __attribute__((ext_vector_type(16))) float f32x16;

__device__ __forceinline__ unsigned short bf16_rne(float f) {
    union { float f; unsigned int u; } c; c.f = f;
    unsigned int u = c.u;
    u += 0x7fffu + ((u >> 16) & 1u);
    return (unsigned short)(u >> 16);
}

__device__ __forceinline__ float bf16_to_f(unsigned short h) {
    union { unsigned int u; float f; } c;
    c.u = ((unsigned int)h) << 16;
    return c.f;
}

// ---------------- Kernel 1: build Wpk (512x512 bf16, chunked layout) ----------------
// Thread (i = blockIdx.y, j = blockIdx.x*256+tid) computes C[i][j], stores
// B[j][i] (symmetry) at chunk unit (j>>3)*512 + i, elem j&7. Lanes 0-7
// (consecutive j) write one contiguous 16B unit -> merged stores.
__global__ __launch_bounds__(256) void build_wpk(const float* __restrict__ v,
                                                 const int* __restrict__ f2f,
                                                 unsigned short* __restrict__ Wpk) {
    __shared__ float a_lds[FK];          // 4.8 KB
    __shared__ float c_lds[256 * 44];    // 45 KB (pad 40->44)

    const int i   = blockIdx.y;
    const int j0  = blockIdx.x * 256;
    const int tid = threadIdx.x;
    const int fi  = f2f[i];

    for (int q = tid; q < FK; q += 256) a_lds[q] = v[(size_t)i * FK + q];
    for (int q = tid; q < 2560; q += 256) {
        const int jl = q / 10, c4 = q % 10;
        *(float4*)&c_lds[jl * 44 + c4 * 4] =
            *(const float4*)&v[(size_t)(j0 + jl) * FK + fi * KDIM + c4 * 4];
    }
    __syncthreads();

    const int j  = j0 + tid;
    const int fj = f2f[j];
    const float4* a = (const float4*)&a_lds[fj * KDIM];
    const float4* c = (const float4*)&c_lds[tid * 44];
    float acc = 0.f;
#pragma unroll
    for (int q = 0; q < KDIM / 4; ++q) {
        float4 av = a[q], cv = c[q];
        acc = fmaf(av.x, cv.x, acc);
        acc = fmaf(av.y, cv.y, acc);
        acc = fmaf(av.z, cv.z, acc);
        acc = fmaf(av.w, cv.w, acc);
    }
    const unsigned short val = (i == j) ? (unsigned short)0 : bf16_rne(0.5f * acc);
    Wpk[((size_t)(j >> 3) * 512 + i) * 8 + (j & 7)] = val;
}

// ---------------- Kernel 2: fused GEMM + quadratic-form epilogue ----------------
// grid: 256 blocks x 512 threads (8 waves), 1 block/CU, single round.
// Wave (wm=w&1, wn=w>>1): rows [wm*64,+64), cols [wn*128,+128) = 2mi x 4ci
// frags of 32x32x16 (acc 128 AGPR). As: kc-major units, unit(kc,r) =
// kc*128 + (r^(kc&7)). B direct global->VGPR from Wpk (unit (ks*512+col)).
__global__ __launch_bounds__(512, 1) void ffm_fused(const float* __restrict__ X,
                                                    const unsigned short* __restrict__ Wpk,
                                                    const float* __restrict__ w1,
                                                    const float* __restrict__ bvec,
                                                    float* __restrict__ out) {
    __shared__ __align__(16) unsigned short As[BM * N_FEAT];      // 128 KB
    __shared__ float part[4 * BM];                                // 2 KB

    const int tid  = threadIdx.x;
    const int lane = tid & 63;
    const int wave = tid >> 6;      // 0..7
    const int half = lane >> 5;     // 0/1
    const int l31  = lane & 31;
    const int wm   = wave & 1;      // row half
    const int wn   = wave >> 1;     // col quarter 0..3

    const size_t row0 = (size_t)blockIdx.x * BM;

    // Per-lane B base: unit = (step*4 + si*2 + half)*512 + wn*128 + ci*32 + l31.
    const unsigned short* wp = Wpk + ((size_t)half * 512 + wn * 128 + l31) * 8;

    // ---- Prologue: build As (X block, bf16, kc-major + XOR swizzle), rolled ----
    {
        const float4* X4 = (const float4*)(X + row0 * N_FEAT);
#pragma unroll 2
        for (int u = 0; u < 16; ++u) {
            const int g  = u * 512 + tid;
            const int r  = g >> 6;      // wave-uniform row 0..127
            const int kc = g & 63;      // = lane: 16B chunk in row
            float4 f0 = X4[r * 128 + kc * 2];
            float4 f1 = X4[r * 128 + kc * 2 + 1];
            union { unsigned short us[8]; short8 v; } pk;
            pk.us[0] = bf16_rne(f0.x);
            pk.us[1] = bf16_rne(f0.y);
            pk.us[2] = bf16_rne(f0.z);
            pk.us[3] = bf16_rne(f0.w);
            pk.us[4] = bf16_rne(f1.x);
            pk.us[5] = bf16_rne(f1.y);
            pk.us[6] = bf16_rne(f1.z);
            pk.us[7] = bf16_rne(f1.w);
            *(short8*)(As + ((size_t)kc * BM + (r ^ (kc & 7))) * 8) = pk.v;
        }
    }
    asm volatile("s_waitcnt lgkmcnt(0)" ::: "memory");
    __builtin_amdgcn_s_barrier();          // As visible to all waves

    f32x16 acc[2][4];
#pragma unroll
    for (int mi = 0; mi < 2; ++mi)
#pragma unroll
        for (int ci = 0; ci < 4; ++ci)
#pragma unroll
            for (int r = 0; r < 16; ++r) acc[mi][ci][r] = 0.f;

    short8 fb[2][2][4];   // [parity slot][si][ci], prefetch distance 2
    short8 fa[2][2][2];   // [parity slot][si][mi], prefetch distance 1

    // ---- Prime: fb(0)->slot0, fb(1)->slot1, fa(0)->slot0 ----
#pragma unroll
    for (int si = 0; si < 2; ++si)
#pragma unroll
        for (int ci = 0; ci < 4; ++ci) {
            fb[0][si][ci] = *(const short8*)(wp + ((size_t)((si * 2) * 512 + ci * 32)) * 8);
            fb[1][si][ci] = *(const short8*)(wp + ((size_t)((4 + si * 2) * 512 + ci * 32)) * 8);
        }
#pragma unroll
    for (int si = 0; si < 2; ++si) {
        const int kr = si * 2 + half;           // kcg for step 0; ksw = kr
#pragma unroll
        for (int mi = 0; mi < 2; ++mi) {
            const int row = wm * 64 + mi * 32 + l31;
            fa[0][si][mi] = *(const short8*)(As + ((size_t)kr * BM + (row ^ kr)) * 8);
        }
    }

    // Roaming pointers: wpt/at track step t's base (t even).
    const unsigned short* wpt = wp;
    const unsigned short* at  = (const unsigned short*)As;

    // ---- Main loop: 7 iterations, 2 steps each (steps 0..13), rolled ----
#pragma unroll 1
    for (int t = 0; t < 14; t += 2) {
        // 1) fa(t+1) -> slot1  (kcg_rel = 4+si*2+half; t even => ksw = rel&7)
#pragma unroll
        for (int si = 0; si < 2; ++si) {
            const int kr = 4 + si * 2 + half;
#pragma unroll
            for (int mi = 0; mi < 2; ++mi) {
                const int row = wm * 64 + mi * 32 + l31;
                fa[1][si][mi] = *(const short8*)(at + ((size_t)kr * BM + (row ^ (kr & 7))) * 8);
            }
        }
        // 2) MFMA(t) on slot0
#pragma unroll
        for (int si = 0; si < 2; ++si)
#pragma unroll
            for (int mi = 0; mi < 2; ++mi)
#pragma unroll
                for (int ci = 0; ci < 4; ++ci)
                    acc[mi][ci] = __builtin_amdgcn_mfma_f32_32x32x16_bf16(
                        fa[0][si][mi], fb[0][si][ci], acc[mi][ci], 0, 0, 0);
        // 3) fb(t+2) -> slot0
#pragma unroll
        for (int si = 0; si < 2; ++si)
#pragma unroll
            for (int ci = 0; ci < 4; ++ci)
                fb[0][si][ci] = *(const short8*)(wpt +
                    ((size_t)((8 + si * 2) * 512 + ci * 32)) * 8);
        // 4) fa(t+2) -> slot0  (kcg_rel = 8+si*2+half; ksw = (si*2+half))
#pragma unroll
        for (int si = 0; si < 2; ++si) {
            const int kr = 8 + si * 2 + half;
            const int ks = (si * 2 + half);
#pragma unroll
            for (int mi = 0; mi < 2; ++mi) {
                const int row = wm * 64 + mi * 32 + l31;
                fa[0][si][mi] = *(const short8*)(at + ((size_t)kr * BM + (row ^ ks)) * 8);
            }
        }
        // 5) MFMA(t+1) on slot1
#pragma unroll
        for (int si = 0; si < 2; ++si)
#pragma unroll
            for (int mi = 0; mi < 2; ++mi)
#pragma unroll
                for (int ci = 0; ci < 4; ++ci)
                    acc[mi][ci] = __builtin_amdgcn_mfma_f32_32x32x16_bf16(
                        fa[1][si][mi], fb[1][si][ci], acc[mi][ci], 0, 0, 0);
        // 6) fb(t+3) -> slot1
#pragma unroll
        for (int si = 0; si < 2; ++si)
#pragma unroll
            for (int ci = 0; ci < 4; ++ci)
                fb[1][si][ci] = *(const short8*)(wpt +
                    ((size_t)((12 + si * 2) * 512 + ci * 32)) * 8);

        wpt += (size_t)8 * 512 * 8;   // advance 2 steps (8 kc-chunks)
        at  += (size_t)8 * BM * 8;
    }

    // ---- Tail: steps 14,15 (fb(14)/fa(14) in slot0, fb(15) in slot1 from last body)
#pragma unroll
    for (int si = 0; si < 2; ++si) {
        const int kr = 4 + si * 2 + half;       // kcg 60+.. ; 56%8==0 => ksw = kr&7
#pragma unroll
        for (int mi = 0; mi < 2; ++mi) {
            const int row = wm * 64 + mi * 32 + l31;
            fa[1][si][mi] = *(const short8*)(at + ((size_t)kr * BM + (row ^ (kr & 7))) * 8);
        }
    }
#pragma unroll
    for (int si = 0; si < 2; ++si)
#pragma unroll
        for (int mi = 0; mi < 2; ++mi)
#pragma unroll
            for (int ci = 0; ci < 4; ++ci)
                acc[mi][ci] = __builtin_amdgcn_mfma_f32_32x32x16_bf16(
                    fa[0][si][mi], fb[0][si][ci], acc[mi][ci], 0, 0, 0);
#pragma unroll
    for (int si = 0; si < 2; ++si)
#pragma unroll
        for (int mi = 0; mi < 2; ++mi)
#pragma unroll
            for (int ci = 0; ci < 4; ++ci)
                acc[mi][ci] = __builtin_amdgcn_mfma_f32_32x32x16_bf16(
                    fa[1][si][mi], fb[1][si][ci], acc[mi][ci], 0, 0, 0);

    // ---- Epilogue: rs[row] = sum_col x[row][col]*(y + w1), x-hat from As (bf16).
    // C/D 32x32 layout: col = l31 (+ci*32+wn*128), row = (reg&3)+8*(reg>>2)+4*half
    // (+wm*64+mi*32).
    float w1v[4];
#pragma unroll
    for (int ci = 0; ci < 4; ++ci) w1v[ci] = w1[wn * 128 + ci * 32 + l31];
    const float bias = bvec[0];

    float rs[2][16];
#pragma unroll
    for (int mi = 0; mi < 2; ++mi) {
#pragma unroll
        for (int reg = 0; reg < 16; ++reg) {
            const int row = wm * 64 + mi * 32 + (reg & 3) + 8 * (reg >> 2) + 4 * half;
            float s = 0.f;
#pragma unroll
            for (int ci = 0; ci < 4; ++ci) {
                const int gc = wn * 128 + ci * 32 + l31;      // k-index 0..511
                const int kc = gc >> 3;
                const float xf = bf16_to_f(As[((size_t)kc * BM + (row ^ (kc & 7))) * 8 + (gc & 7)]);
                s = fmaf(xf, acc[mi][ci][reg] + w1v[ci], s);
            }
            rs[mi][reg] = s;
        }
    }

    // Reduce over the 32 cols held across l31 (each 32-lane group = one row set).
#pragma unroll
    for (int mi = 0; mi < 2; ++mi)
#pragma unroll
        for (int reg = 0; reg < 16; ++reg) {
            float r = rs[mi][reg];
#pragma unroll
            for (int off = 1; off < 32; off <<= 1)
                r += __shfl_xor(r, off, 32);
            rs[mi][reg] = r;
        }
    if (l31 == 0) {
#pragma unroll
        for (int mi = 0; mi < 2; ++mi)
#pragma unroll
            for (int reg = 0; reg < 16; ++reg) {
                const int row = wm * 64 + mi * 32 + (reg & 3) + 8 * (reg >> 2) + 4 * half;
                part[wn * BM + row] = rs[mi][reg];
            }
    }
    __syncthreads();

    if (tid < BM) {
        float tsum = bias;
#pragma unroll
        for (int q = 0; q < 4; ++q) tsum += part[q * BM + tid];
        out[row0 + tid] = 1.0f / (1.0f + expf(-tsum));
    }
}

extern "C" void kernel_launch(void* const* d_in, const int* in_sizes, int n_in,
                              void* d_out, int out_size, void* d_ws, size_t ws_size,
                              hipStream_t stream) {
    const float* X   = (const float*)d_in[0];   // 32768 x 512
    const float* w1  = (const float*)d_in[1];   // 512
    const float* b   = (const float*)d_in[2];   // 1
    const float* v   = (const float*)d_in[3];   // 512 x 30 x 40
    const int*   f2f = (const int*)d_in[4];     // 512
    float* out = (float*)d_out;                 // 32768

    unsigned short* Wpk = (unsigned short*)d_ws;   // 512 KB scratch (chunked layout)

    build_wpk<<<dim3(2, N_FEAT), 256, 0, stream>>>(v, f2f, Wpk);
    ffm_fused<<<B_ROWS / BM, 512, 0, stream>>>(X, Wpk, w1, b, out);
}